// Round 5
// baseline (195.274 us; speedup 1.0000x reference)
//
#include <hip/hip_runtime.h>

// Problem constants (match reference)
#define Dd 16
#define Zd 64
#define Yd 128
#define Xd 128
#define Cd 2

// W is stored bf16-packed (ch0|ch1<<16, 4 B per tap) in (2z,4y,2x) bricks:
// 16 taps * 4 B = 64 B = one cache line per brick.
// addr(z,y,x) [4B units] = (z>>1)<<15 | (y>>2)<<10 | (x>>1)<<4 | (z&1)<<3 | (y&3)<<1 | (x&1)

__device__ __forceinline__ void spline_w(float coord, int size, int* idx4, float* w) {
    int i0 = (int)coord;                       // trunc; coords >= 0 here
    float s = coord - (float)i0;
    s = fminf(fmaxf(s, 0.0f), 1.0f);
#pragma unroll
    for (int j = 0; j < 4; ++j) {
        int k = i0 - 1 + j;
        idx4[j] = min(max(k, 0), size - 1);
    }
    float s2 = s * s, s3 = s2 * s;
    // Catmull-Rom weights (powers @ HERMITE @ CR)
    w[0] = -0.5f * s3 + s2 - 0.5f * s;
    w[1] =  1.5f * s3 - 2.5f * s2 + 1.0f;
    w[2] = -1.5f * s3 + 2.0f * s2 + 0.5f * s;
    w[3] =  0.5f * s3 - 0.5f * s2;
}

// Round-to-nearest-even f32 -> bf16, packed (a low 16, b high 16)
__device__ __forceinline__ unsigned pack_bf16x2(float a, float b) {
    unsigned ua = __float_as_uint(a);
    unsigned ub = __float_as_uint(b);
    ua += 0x7fffu + ((ua >> 16) & 1u);
    ub += 0x7fffu + ((ub >> 16) & 1u);
    return (ua >> 16) | (ub & 0xffff0000u);
}

// Kernel A: contract depth (depth_coord = depth-1 since depths = 1..16) into
// the bricked bf16 volume. One thread -> one uint4 (4 consecutive brick slots).
__global__ void depth_contract_brick_kernel(const float* __restrict__ knots,
                                            const float* __restrict__ depth_p,
                                            uint4* __restrict__ Wv) {
    const int nv4 = Zd * Yd * Xd / 4;          // 262144 uint4
    int t = blockIdx.x * blockDim.x + threadIdx.x;
    if (t >= nv4) return;

    int id[4]; float wd[4];
    spline_w(depth_p[0] - 1.0f, Dd, id, wd);

    const float2* __restrict__ k2 = (const float2*)knots;
    const int slice = Zd * Yd * Xd;            // taps per depth slice

    unsigned packed[4];
#pragma unroll
    for (int e = 0; e < 4; ++e) {
        int u = t * 4 + e;
        int z = ((u >> 15) << 1) | ((u >> 3) & 1);
        int y = (((u >> 10) & 31) << 2) | ((u >> 1) & 3);
        int x = (((u >> 4) & 63) << 1) | (u & 1);
        int lin = (z * Yd + y) * Xd + x;
        float r0 = 0.f, r1 = 0.f;
#pragma unroll
        for (int j = 0; j < 4; ++j) {
            float2 v = k2[id[j] * slice + lin];
            r0 = fmaf(wd[j], v.x, r0);
            r1 = fmaf(wd[j], v.y, r1);
        }
        packed[e] = pack_bf16x2(r0, r1);
    }
    uint4 o; o.x = packed[0]; o.y = packed[1]; o.z = packed[2]; o.w = packed[3];
    Wv[t] = o;
}

// Kernel B: 4 lanes per point; lane q owns x-tap q. 16 independent 4B loads
// per lane from the bricked, L2-resident 4 MB volume.
__global__ __launch_bounds__(256, 8)
void gather_eval_brick_kernel(const float* __restrict__ idx,
                              const unsigned* __restrict__ W,
                              float* __restrict__ out, int n_pts) {
    int t = blockIdx.x * blockDim.x + threadIdx.x;
    int n = t >> 2;            // point index
    int q = t & 3;             // x-tap
    if (n >= n_pts) return;

    float zc = idx[n * 3 + 0];
    float yc = idx[n * 3 + 1];
    float xc = idx[n * 3 + 2];

    int iz[4], iy[4], ix[4];
    float wz[4], wy[4], wx[4];
    spline_w(zc, Zd, iz, wz);
    spline_w(yc, Yd, iy, wy);
    spline_w(xc, Xd, ix, wx);

    const int xq = ix[q];
    const int xcomp = ((xq >> 1) << 4) | (xq & 1);
    const float wxq = wx[q];

    int za[4], yb_[4];
#pragma unroll
    for (int a = 0; a < 4; ++a) za[a]  = ((iz[a] >> 1) << 15) | ((iz[a] & 1) << 3);
#pragma unroll
    for (int b = 0; b < 4; ++b) yb_[b] = ((iy[b] >> 2) << 10) | ((iy[b] & 3) << 1);

    float r0 = 0.0f, r1 = 0.0f;
#pragma unroll
    for (int a = 0; a < 4; ++a) {
#pragma unroll
        for (int b = 0; b < 4; ++b) {
            unsigned w = W[za[a] + yb_[b] + xcomp];
            float c0 = __uint_as_float(w << 16);
            float c1 = __uint_as_float(w & 0xffff0000u);
            float wzy = wz[a] * wy[b];
            r0 = fmaf(wzy, c0, r0);
            r1 = fmaf(wzy, c1, r1);
        }
    }
    r0 *= wxq;
    r1 *= wxq;

    // Reduce across the quad
    r0 += __shfl_xor(r0, 1); r0 += __shfl_xor(r0, 2);
    r1 += __shfl_xor(r1, 1); r1 += __shfl_xor(r1, 2);

    if (q == 0) {
        float2 o; o.x = r0; o.y = r1;
        ((float2*)out)[n] = o;
    }
}

// Fallback: fully fused f32 (used only if d_ws can't hold the 4 MB volume).
__global__ void fused_kernel(const float* __restrict__ idx,
                             const float* __restrict__ knots,
                             const float* __restrict__ depth_p,
                             float* __restrict__ out, int n_pts) {
    int n = blockIdx.x * blockDim.x + threadIdx.x;
    if (n >= n_pts) return;
    int id[4]; float wd[4];
    spline_w(depth_p[0] - 1.0f, Dd, id, wd);
    int iz[4], iy[4], ix[4];
    float wz[4], wy[4], wx[4];
    spline_w(idx[n * 3 + 0], Zd, iz, wz);
    spline_w(idx[n * 3 + 1], Yd, iy, wy);
    spline_w(idx[n * 3 + 2], Xd, ix, wx);
    float acc0 = 0.0f, acc1 = 0.0f;
    for (int dd = 0; dd < 4; ++dd) {
        const float* base = knots + (size_t)id[dd] * Zd * Yd * Xd * Cd;
        float d0 = 0.0f, d1 = 0.0f;
        for (int a = 0; a < 4; ++a)
            for (int bb = 0; bb < 4; ++bb) {
                const float2* row = (const float2*)(base + ((size_t)(iz[a] * Yd + iy[bb]) * Xd) * Cd);
                float r0 = 0.0f, r1 = 0.0f;
                for (int qq = 0; qq < 4; ++qq) {
                    float2 v = row[ix[qq]];
                    r0 = fmaf(wx[qq], v.x, r0);
                    r1 = fmaf(wx[qq], v.y, r1);
                }
                float wzy = wz[a] * wy[bb];
                d0 = fmaf(wzy, r0, d0);
                d1 = fmaf(wzy, r1, d1);
            }
        acc0 = fmaf(wd[dd], d0, acc0);
        acc1 = fmaf(wd[dd], d1, acc1);
    }
    out[n * 2 + 0] = acc0;
    out[n * 2 + 1] = acc1;
}

extern "C" void kernel_launch(void* const* d_in, const int* in_sizes, int n_in,
                              void* d_out, int out_size, void* d_ws, size_t ws_size,
                              hipStream_t stream) {
    const float* idx   = (const float*)d_in[0];   // [N,3] f32
    const float* knots = (const float*)d_in[1];   // [16,64,128,128,2] f32
    const float* depth = (const float*)d_in[2];   // scalar f32
    float* out = (float*)d_out;                   // [N,2] f32
    const int n_pts = in_sizes[0] / 3;

    const size_t wBytes = (size_t)Zd * Yd * Xd * Cd * 2;   // 4 MB bf16
    if (ws_size >= wBytes) {
        unsigned* W = (unsigned*)d_ws;
        const int nv4 = Zd * Yd * Xd / 4;
        depth_contract_brick_kernel<<<(nv4 + 255) / 256, 256, 0, stream>>>(knots, depth, (uint4*)W);
        const int nthreads = n_pts * 4;
        gather_eval_brick_kernel<<<(nthreads + 255) / 256, 256, 0, stream>>>(idx, W, out, n_pts);
    } else {
        fused_kernel<<<(n_pts + 255) / 256, 256, 0, stream>>>(idx, knots, depth, out, n_pts);
    }
}

// Round 6
// 192.757 us; speedup vs baseline: 1.0131x; 1.0131x over previous
//
#include <hip/hip_runtime.h>

// Problem constants (match reference)
#define Dd 16
#define Zd 64
#define Yd 128
#define Xd 128
#define Cd 2

// W layout: V[y][x][z], one packed bf16x2 (ch0|ch1<<16) per tap, z INNERMOST.
// 128*128*64*4 B = 4 MB (fits each XCD's 4 MB L2). A 16B load at (y,x,z0)
// covers all 4 z-taps (z-span is consecutive; coords never clamp in-range).

typedef unsigned uint4v __attribute__((ext_vector_type(4)));
struct __attribute__((packed, aligned(4))) U16A { uint4v v; };   // 4B-aligned 16B load

__device__ __forceinline__ void spline_w(float coord, int size, int* idx4, float* w) {
    int i0 = (int)coord;
    float s = coord - (float)i0;
    s = fminf(fmaxf(s, 0.0f), 1.0f);
#pragma unroll
    for (int j = 0; j < 4; ++j) {
        int k = i0 - 1 + j;
        idx4[j] = min(max(k, 0), size - 1);
    }
    float s2 = s * s, s3 = s2 * s;
    w[0] = -0.5f * s3 + s2 - 0.5f * s;
    w[1] =  1.5f * s3 - 2.5f * s2 + 1.0f;
    w[2] = -1.5f * s3 + 2.0f * s2 + 0.5f * s;
    w[3] =  0.5f * s3 - 0.5f * s2;
}

__device__ __forceinline__ unsigned pack_bf16x2(float a, float b) {
    unsigned ua = __float_as_uint(a);
    unsigned ub = __float_as_uint(b);
    ua += 0x7fffu + ((ua >> 16) & 1u);
    ub += 0x7fffu + ((ub >> 16) & 1u);
    return (ua >> 16) | (ub & 0xffff0000u);
}

// Kernel A: depth-contract (depth_coord = depth-1, depths are 1..16) into the
// z-innermost bf16 volume via LDS transpose. Block = (y, 32-wide x chunk).
// Phase 1: coalesced knot reads (lanes span x), accumulate 4 depths, pack.
// Phase 2: coalesced V writes (lanes span z).
__global__ __launch_bounds__(256) void depth_contract_zinner(const float* __restrict__ knots,
                                                             const float* __restrict__ depth_p,
                                                             unsigned* __restrict__ V) {
    __shared__ unsigned L[32 * 65];            // [x][z], stride 65 breaks conflicts
    const int b = blockIdx.x;                  // 512 blocks
    const int y = b >> 2;
    const int x0 = (b & 3) * 32;
    const int tid = threadIdx.x;

    int id[4]; float wd[4];
    spline_w(depth_p[0] - 1.0f, Dd, id, wd);

    const float2* __restrict__ k2 = (const float2*)knots;

#pragma unroll
    for (int it = 0; it < 8; ++it) {
        int i = it * 256 + tid;
        int x = i & 31;                        // lanes span x -> coalesced
        int z = i >> 5;
        float r0 = 0.f, r1 = 0.f;
#pragma unroll
        for (int j = 0; j < 4; ++j) {
            float2 v = k2[((id[j] * Zd + z) * Yd + y) * Xd + x0 + x];
            r0 = fmaf(wd[j], v.x, r0);
            r1 = fmaf(wd[j], v.y, r1);
        }
        L[x * 65 + z] = pack_bf16x2(r0, r1);
    }
    __syncthreads();

#pragma unroll
    for (int it = 0; it < 8; ++it) {
        int xs = it * 4 + (tid >> 6);
        int z = tid & 63;                      // lanes span z -> coalesced 256B
        V[((y * Xd + x0 + xs) * Zd) + z] = L[xs * 65 + z];
    }
}

// Kernel B: 4 lanes per point; lane q owns x-tap q. Per lane: 4 independent
// 16B loads (one per y-tap), each covering all 4 z-taps. 16 lane-addresses
// per point (was 64).
__global__ __launch_bounds__(256) void gather_eval_zquad(const float* __restrict__ idx,
                                                         const unsigned* __restrict__ V,
                                                         float* __restrict__ out, int n_pts) {
    int t = blockIdx.x * blockDim.x + threadIdx.x;
    int n = t >> 2;            // point index
    int q = t & 3;             // x-tap
    if (n >= n_pts) return;

    float zc = idx[n * 3 + 0];
    float yc = idx[n * 3 + 1];
    float xc = idx[n * 3 + 2];

    // z: consecutive 4-span starting at z0 (no clamp fires for in-range input)
    int i0z = (int)zc;
    float sz = fminf(fmaxf(zc - (float)i0z, 0.0f), 1.0f);
    int z0 = min(max(i0z - 1, 0), Zd - 4);
    float sz2 = sz * sz, sz3 = sz2 * sz;
    float wz0 = -0.5f * sz3 + sz2 - 0.5f * sz;
    float wz1 =  1.5f * sz3 - 2.5f * sz2 + 1.0f;
    float wz2 = -1.5f * sz3 + 2.0f * sz2 + 0.5f * sz;
    float wz3 =  0.5f * sz3 - 0.5f * sz2;

    int iy[4]; float wy[4];
    spline_w(yc, Yd, iy, wy);

    int ix[4]; float wx[4];
    spline_w(xc, Xd, ix, wx);
    const int xq = ix[q];
    const float wxq = wx[q];

    // 4 independent 16B loads (one per y-tap)
    const U16A* p0 = (const U16A*)(V + ((iy[0] * Xd + xq) * Zd + z0));
    const U16A* p1 = (const U16A*)(V + ((iy[1] * Xd + xq) * Zd + z0));
    const U16A* p2 = (const U16A*)(V + ((iy[2] * Xd + xq) * Zd + z0));
    const U16A* p3 = (const U16A*)(V + ((iy[3] * Xd + xq) * Zd + z0));
    uint4v u0 = p0->v;
    uint4v u1 = p1->v;
    uint4v u2 = p2->v;
    uint4v u3 = p3->v;

    float r0 = 0.0f, r1 = 0.0f;
    {
        float c0, c1;
#define ZDOT(u)                                                                 \
        c0 = wz0 * __uint_as_float((u).x << 16) + wz1 * __uint_as_float((u).y << 16)   \
           + wz2 * __uint_as_float((u).z << 16) + wz3 * __uint_as_float((u).w << 16);  \
        c1 = wz0 * __uint_as_float((u).x & 0xffff0000u) + wz1 * __uint_as_float((u).y & 0xffff0000u) \
           + wz2 * __uint_as_float((u).z & 0xffff0000u) + wz3 * __uint_as_float((u).w & 0xffff0000u);
        ZDOT(u0); r0 = fmaf(wy[0], c0, r0); r1 = fmaf(wy[0], c1, r1);
        ZDOT(u1); r0 = fmaf(wy[1], c0, r0); r1 = fmaf(wy[1], c1, r1);
        ZDOT(u2); r0 = fmaf(wy[2], c0, r0); r1 = fmaf(wy[2], c1, r1);
        ZDOT(u3); r0 = fmaf(wy[3], c0, r0); r1 = fmaf(wy[3], c1, r1);
#undef ZDOT
    }
    r0 *= wxq;
    r1 *= wxq;

    // Reduce across the quad
    r0 += __shfl_xor(r0, 1); r0 += __shfl_xor(r0, 2);
    r1 += __shfl_xor(r1, 1); r1 += __shfl_xor(r1, 2);

    if (q == 0) {
        float2 o; o.x = r0; o.y = r1;
        ((float2*)out)[n] = o;
    }
}

// Fallback: fully fused f32 (used only if d_ws can't hold the 4 MB volume).
__global__ void fused_kernel(const float* __restrict__ idx,
                             const float* __restrict__ knots,
                             const float* __restrict__ depth_p,
                             float* __restrict__ out, int n_pts) {
    int n = blockIdx.x * blockDim.x + threadIdx.x;
    if (n >= n_pts) return;
    int id[4]; float wd[4];
    spline_w(depth_p[0] - 1.0f, Dd, id, wd);
    int iz[4], iy[4], ix[4];
    float wz[4], wy[4], wx[4];
    spline_w(idx[n * 3 + 0], Zd, iz, wz);
    spline_w(idx[n * 3 + 1], Yd, iy, wy);
    spline_w(idx[n * 3 + 2], Xd, ix, wx);
    float acc0 = 0.0f, acc1 = 0.0f;
    for (int dd = 0; dd < 4; ++dd) {
        const float* base = knots + (size_t)id[dd] * Zd * Yd * Xd * Cd;
        float d0 = 0.0f, d1 = 0.0f;
        for (int a = 0; a < 4; ++a)
            for (int bb = 0; bb < 4; ++bb) {
                const float2* row = (const float2*)(base + ((size_t)(iz[a] * Yd + iy[bb]) * Xd) * Cd);
                float r0 = 0.0f, r1 = 0.0f;
                for (int qq = 0; qq < 4; ++qq) {
                    float2 v = row[ix[qq]];
                    r0 = fmaf(wx[qq], v.x, r0);
                    r1 = fmaf(wx[qq], v.y, r1);
                }
                float wzy = wz[a] * wy[bb];
                d0 = fmaf(wzy, r0, d0);
                d1 = fmaf(wzy, r1, d1);
            }
        acc0 = fmaf(wd[dd], d0, acc0);
        acc1 = fmaf(wd[dd], d1, acc1);
    }
    out[n * 2 + 0] = acc0;
    out[n * 2 + 1] = acc1;
}

extern "C" void kernel_launch(void* const* d_in, const int* in_sizes, int n_in,
                              void* d_out, int out_size, void* d_ws, size_t ws_size,
                              hipStream_t stream) {
    const float* idx   = (const float*)d_in[0];   // [N,3] f32
    const float* knots = (const float*)d_in[1];   // [16,64,128,128,2] f32
    const float* depth = (const float*)d_in[2];   // scalar f32
    float* out = (float*)d_out;                   // [N,2] f32
    const int n_pts = in_sizes[0] / 3;

    const size_t wBytes = (size_t)Zd * Yd * Xd * Cd * 2;   // 4 MB bf16
    if (ws_size >= wBytes) {
        unsigned* V = (unsigned*)d_ws;
        depth_contract_zinner<<<512, 256, 0, stream>>>(knots, depth, V);
        const int nthreads = n_pts * 4;
        gather_eval_zquad<<<(nthreads + 255) / 256, 256, 0, stream>>>(idx, V, out, n_pts);
    } else {
        fused_kernel<<<(n_pts + 255) / 256, 256, 0, stream>>>(idx, knots, depth, out, n_pts);
    }
}

// Round 7
// 192.449 us; speedup vs baseline: 1.0147x; 1.0016x over previous
//
#include <hip/hip_runtime.h>

// Problem constants (match reference)
#define Dd 16
#define Zd 64
#define Yd 128
#define Xd 128
#define Cd 2

// V layout: V[y][x][z], one packed bf16x2 (ch0|ch1<<16) per tap, z INNERMOST.
// 128*128*64*4 B = 4 MB (fits each XCD's 4 MB L2). A 16B load at (y,x,z0)
// covers all 4 z-taps (z-span is consecutive; in-range coords never clamp).

typedef unsigned uint4v __attribute__((ext_vector_type(4)));
struct __attribute__((packed, aligned(4))) U16A { uint4v v; };   // 4B-aligned 16B load

__device__ __forceinline__ void spline_w(float coord, int size, int* idx4, float* w) {
    int i0 = (int)coord;
    float s = coord - (float)i0;
    s = fminf(fmaxf(s, 0.0f), 1.0f);
#pragma unroll
    for (int j = 0; j < 4; ++j) {
        int k = i0 - 1 + j;
        idx4[j] = min(max(k, 0), size - 1);
    }
    float s2 = s * s, s3 = s2 * s;
    w[0] = -0.5f * s3 + s2 - 0.5f * s;
    w[1] =  1.5f * s3 - 2.5f * s2 + 1.0f;
    w[2] = -1.5f * s3 + 2.0f * s2 + 0.5f * s;
    w[3] =  0.5f * s3 - 0.5f * s2;
}

__device__ __forceinline__ unsigned pack_bf16x2(float a, float b) {
    unsigned ua = __float_as_uint(a);
    unsigned ub = __float_as_uint(b);
    ua += 0x7fffu + ((ua >> 16) & 1u);
    ub += 0x7fffu + ((ub >> 16) & 1u);
    return (ua >> 16) | (ub & 0xffff0000u);
}

// Kernel A: depth-contract (depth_coord = depth-1 since depths = 1..16) into
// the z-innermost bf16 volume via LDS transpose. Block = (y, 32-wide x chunk).
__global__ __launch_bounds__(256) void depth_contract_zinner(const float* __restrict__ knots,
                                                             const float* __restrict__ depth_p,
                                                             unsigned* __restrict__ V) {
    __shared__ unsigned L[32 * 65];            // [x][z], stride 65 breaks conflicts
    const int b = blockIdx.x;                  // 512 blocks
    const int y = b >> 2;
    const int x0 = (b & 3) * 32;
    const int tid = threadIdx.x;

    int id[4]; float wd[4];
    spline_w(depth_p[0] - 1.0f, Dd, id, wd);

    const float2* __restrict__ k2 = (const float2*)knots;

#pragma unroll
    for (int it = 0; it < 8; ++it) {
        int i = it * 256 + tid;
        int x = i & 31;                        // lanes span x -> coalesced
        int z = i >> 5;
        float r0 = 0.f, r1 = 0.f;
#pragma unroll
        for (int j = 0; j < 4; ++j) {
            float2 v = k2[((id[j] * Zd + z) * Yd + y) * Xd + x0 + x];
            r0 = fmaf(wd[j], v.x, r0);
            r1 = fmaf(wd[j], v.y, r1);
        }
        L[x * 65 + z] = pack_bf16x2(r0, r1);
    }
    __syncthreads();

#pragma unroll
    for (int it = 0; it < 8; ++it) {
        int xs = it * 4 + (tid >> 6);
        int z = tid & 63;                      // lanes span z -> coalesced 256B
        V[((y * Xd + x0 + xs) * Zd) + z] = L[xs * 65 + z];
    }
}

// Kernel B: ONE thread per point. 16 independent 16B z-quad loads (4 y-taps x
// 4 x-taps), then the full (z,y,x) contraction in-register. No quad shuffles,
// no redundant weight computation.
__global__ __launch_bounds__(256, 4)
void gather_eval_point(const float* __restrict__ idx,
                       const unsigned* __restrict__ V,
                       float* __restrict__ out, int n_pts) {
    int n = blockIdx.x * blockDim.x + threadIdx.x;
    if (n >= n_pts) return;

    float zc = idx[n * 3 + 0];
    float yc = idx[n * 3 + 1];
    float xc = idx[n * 3 + 2];

    // z: consecutive 4-span starting at z0 (no clamp fires for in-range input)
    int i0z = (int)zc;
    float sz = fminf(fmaxf(zc - (float)i0z, 0.0f), 1.0f);
    int z0 = min(max(i0z - 1, 0), Zd - 4);
    float sz2 = sz * sz, sz3 = sz2 * sz;
    float wz0 = -0.5f * sz3 + sz2 - 0.5f * sz;
    float wz1 =  1.5f * sz3 - 2.5f * sz2 + 1.0f;
    float wz2 = -1.5f * sz3 + 2.0f * sz2 + 0.5f * sz;
    float wz3 =  0.5f * sz3 - 0.5f * sz2;

    int iy[4]; float wy[4];
    spline_w(yc, Yd, iy, wy);
    int ix[4]; float wx[4];
    spline_w(xc, Xd, ix, wx);

    // 16 independent 16B loads, all issued before any use (deep MLP)
    uint4v u[16];
#pragma unroll
    for (int a = 0; a < 4; ++a) {
        const int rowa = iy[a] * (Xd * Zd) + z0;
#pragma unroll
        for (int b = 0; b < 4; ++b) {
            u[a * 4 + b] = ((const U16A*)(V + (rowa + ix[b] * Zd)))->v;
        }
    }

    float r0 = 0.0f, r1 = 0.0f;
#pragma unroll
    for (int a = 0; a < 4; ++a) {
#pragma unroll
        for (int b = 0; b < 4; ++b) {
            uint4v uu = u[a * 4 + b];
            float c0 = wz0 * __uint_as_float(uu.x << 16)
                     + wz1 * __uint_as_float(uu.y << 16)
                     + wz2 * __uint_as_float(uu.z << 16)
                     + wz3 * __uint_as_float(uu.w << 16);
            float c1 = wz0 * __uint_as_float(uu.x & 0xffff0000u)
                     + wz1 * __uint_as_float(uu.y & 0xffff0000u)
                     + wz2 * __uint_as_float(uu.z & 0xffff0000u)
                     + wz3 * __uint_as_float(uu.w & 0xffff0000u);
            float wyx = wy[a] * wx[b];
            r0 = fmaf(wyx, c0, r0);
            r1 = fmaf(wyx, c1, r1);
        }
    }

    float2 o; o.x = r0; o.y = r1;
    ((float2*)out)[n] = o;
}

// Fallback: fully fused f32 (used only if d_ws can't hold the 4 MB volume).
__global__ void fused_kernel(const float* __restrict__ idx,
                             const float* __restrict__ knots,
                             const float* __restrict__ depth_p,
                             float* __restrict__ out, int n_pts) {
    int n = blockIdx.x * blockDim.x + threadIdx.x;
    if (n >= n_pts) return;
    int id[4]; float wd[4];
    spline_w(depth_p[0] - 1.0f, Dd, id, wd);
    int iz[4], iy[4], ix[4];
    float wz[4], wy[4], wx[4];
    spline_w(idx[n * 3 + 0], Zd, iz, wz);
    spline_w(idx[n * 3 + 1], Yd, iy, wy);
    spline_w(idx[n * 3 + 2], Xd, ix, wx);
    float acc0 = 0.0f, acc1 = 0.0f;
    for (int dd = 0; dd < 4; ++dd) {
        const float* base = knots + (size_t)id[dd] * Zd * Yd * Xd * Cd;
        float d0 = 0.0f, d1 = 0.0f;
        for (int a = 0; a < 4; ++a)
            for (int bb = 0; bb < 4; ++bb) {
                const float2* row = (const float2*)(base + ((size_t)(iz[a] * Yd + iy[bb]) * Xd) * Cd);
                float r0 = 0.0f, r1 = 0.0f;
                for (int qq = 0; qq < 4; ++qq) {
                    float2 v = row[ix[qq]];
                    r0 = fmaf(wx[qq], v.x, r0);
                    r1 = fmaf(wx[qq], v.y, r1);
                }
                float wzy = wz[a] * wy[bb];
                d0 = fmaf(wzy, r0, d0);
                d1 = fmaf(wzy, r1, d1);
            }
        acc0 = fmaf(wd[dd], d0, acc0);
        acc1 = fmaf(wd[dd], d1, acc1);
    }
    out[n * 2 + 0] = acc0;
    out[n * 2 + 1] = acc1;
}

extern "C" void kernel_launch(void* const* d_in, const int* in_sizes, int n_in,
                              void* d_out, int out_size, void* d_ws, size_t ws_size,
                              hipStream_t stream) {
    const float* idx   = (const float*)d_in[0];   // [N,3] f32
    const float* knots = (const float*)d_in[1];   // [16,64,128,128,2] f32
    const float* depth = (const float*)d_in[2];   // scalar f32
    float* out = (float*)d_out;                   // [N,2] f32
    const int n_pts = in_sizes[0] / 3;

    const size_t wBytes = (size_t)Zd * Yd * Xd * Cd * 2;   // 4 MB bf16
    if (ws_size >= wBytes) {
        unsigned* V = (unsigned*)d_ws;
        depth_contract_zinner<<<512, 256, 0, stream>>>(knots, depth, V);
        gather_eval_point<<<(n_pts + 255) / 256, 256, 0, stream>>>(idx, V, out, n_pts);
    } else {
        fused_kernel<<<(n_pts + 255) / 256, 256, 0, stream>>>(idx, knots, depth, out, n_pts);
    }
}